// Round 4
// baseline (13398.409 us; speedup 1.0000x reference)
//
// AttentionDecoder on MI355X — round 4 (identical to round 3; prior round hit GPU-acquire timeout)
//
// Pipeline (all on `stream`):
//   memset(counters) -> pack_kernel (f32->f16 pair layouts)
//   keys_kernel  : keys = memory @ Wm, scaled by 2*log2(e), swizzled f16 layout
//   xg_kernel    : xg[t] = x_t @ Wx_dec[0:400] + b_dec  (recurrence-independent part)
//   decoder_kernel: 32 wgs (1 per batch) x 1024 thr, 200-step loop, streams f16
//                   weights from L2; writes attn_seq + alignments (transposed)
//   gru_kernel x2: 256 wgs = 32 groups x 8 members, VGPR-resident weight slices,
//                  1 device-scope sync/step; GRU2 also folds the mel output dense.

#include <hip/hip_runtime.h>
#include <hip/hip_fp16.h>
#include <stdint.h>

#define TDEC 200
#define NB   32

// ---------- ws layout (bytes) ----------
static constexpr size_t OFF_CNT  = 0;                       // cnt1[32], cnt2[32] uints
static constexpr size_t OFF_WXX4 = 256;                     // [50][768][4] uint
static constexpr size_t OFF_WXA4 = OFF_WXX4 + 614400;       // [32][768][4]
static constexpr size_t OFF_WH4  = OFF_WXA4 + 393216;       // [32][768][4]
static constexpr size_t OFF_WQ4  = OFF_WH4  + 393216;       // [32][256][4]
static constexpr size_t OFF_WAL4 = OFF_WQ4  + 131072;       // [64][256][4]
static constexpr size_t OFF_WM4  = OFF_WAL4 + 262144;       // [32][256][4]
static constexpr size_t OFF_WX1P = OFF_WM4  + 131072;       // [128][768] uint
static constexpr size_t OFF_WH1P = OFF_WX1P + 393216;
static constexpr size_t OFF_WX2P = OFF_WH1P + 393216;
static constexpr size_t OFF_WH2P = OFF_WX2P + 393216;
static constexpr size_t OFF_WOUTP= OFF_WH2P + 393216;       // [128][400] uint
static constexpr size_t OFF_KEYS = OFF_WOUTP + 204800;      // __half [32][256][256] (swizzled, *2log2e)
static constexpr size_t OFF_MEME2= OFF_KEYS + 4194304;      // uint [32][32][256][4] (mem pairs along e)
static constexpr size_t OFF_XG   = OFF_MEME2 + 4194304;     // __half [32][200][768]
static constexpr size_t OFF_ATTN = OFF_XG + 9830400;        // float [32][200][256]
static constexpr size_t WS_NEED  = OFF_ATTN + 6553600;      // ~27.2 MB
// aliases (regions dead by the time these run):
static constexpr size_t OFF_Y1   = OFF_XG;                  // float [32][200][256]
static constexpr size_t OFF_Y2   = OFF_KEYS;                // float [32][200][256]

#define AOFF 2560000   // alignments offset in d_out (floats); mel is [32][200][400]

// ---------- helpers ----------
#if __has_builtin(__builtin_amdgcn_exp2f)
#define FEXP2(x) __builtin_amdgcn_exp2f(x)
#else
#define FEXP2(x) exp2f(x)
#endif
#if __has_builtin(__builtin_amdgcn_rcpf)
#define FRCP(x) __builtin_amdgcn_rcpf(x)
#else
#define FRCP(x) (1.0f/(x))
#endif

typedef _Float16 h2t __attribute__((ext_vector_type(2)));

static __device__ __forceinline__ float fdot2u(unsigned a, unsigned b, float c){
  return __builtin_amdgcn_fdot2(__builtin_bit_cast(h2t, a), __builtin_bit_cast(h2t, b), c, false);
}
static __device__ __forceinline__ unsigned pk2(float a, float b){
  auto r = __builtin_amdgcn_cvt_pkrtz(a, b);   // __fp16 ext_vector_type(2) on this ROCm
  return __builtin_bit_cast(unsigned, r);
}
static __device__ __forceinline__ float sigf(float x){        // 1/(1+e^-x)
  return FRCP(1.f + FEXP2(x * -1.44269504f));
}
static __device__ __forceinline__ float tanhf_(float x){      // 1 - 2/(1+e^{2x})
  return 1.f - 2.f * FRCP(1.f + FEXP2(x * 2.88539008f));
}
// NOTE: macro params must NOT be named x/y/z/w — member tokens after '.' get substituted.
#define DOT4(acc, U_, W_) do{ acc = fdot2u((U_).x,(W_).x,acc); acc = fdot2u((U_).y,(W_).y,acc); \
                              acc = fdot2u((U_).z,(W_).z,acc); acc = fdot2u((U_).w,(W_).w,acc);}while(0)

// ---------- pack kernel ----------
// pair layouts: W4[kc][N][i] uint = half2(W[8kc+2i][n], W[8kc+2i+1][n]);  Wp[k2][N] uint.
__global__ __launch_bounds__(256) void pack_kernel(
    const float* Wxd, const float* Whd, const float* Wqm, const float* Walm, const float* Wmm,
    const float* Wx1, const float* Wh1, const float* Wx2, const float* Wh2, const float* Woutm,
    const float* memory, unsigned* ws)
{
  int blk = blockIdx.x, tid = threadIdx.x;
  if (blk < 600){ // WxX4: rows 0..399 of Wx_dec
    unsigned u = blk*256u + tid; int kc = u/3072, r = u%3072, c = r>>2, i = r&3, row = 8*kc+2*i;
    ws[OFF_WXX4/4 + u] = pk2(Wxd[row*768+c], Wxd[(row+1)*768+c]); return; } blk -= 600;
  if (blk < 384){ // WxA4: rows 400..655 of Wx_dec
    unsigned u = blk*256u + tid; int kc = u/3072, r = u%3072, c = r>>2, i = r&3, row = 400+8*kc+2*i;
    ws[OFF_WXA4/4 + u] = pk2(Wxd[row*768+c], Wxd[(row+1)*768+c]); return; } blk -= 384;
  if (blk < 384){ // Wh4
    unsigned u = blk*256u + tid; int kc = u/3072, r = u%3072, c = r>>2, i = r&3, row = 8*kc+2*i;
    ws[OFF_WH4/4 + u] = pk2(Whd[row*768+c], Whd[(row+1)*768+c]); return; } blk -= 384;
  if (blk < 128){ // Wq4
    unsigned u = blk*256u + tid; int kc = u>>10, c = (u>>2)&255, i = u&3, row = 8*kc+2*i;
    ws[OFF_WQ4/4 + u] = pk2(Wqm[row*256+c], Wqm[(row+1)*256+c]); return; } blk -= 128;
  if (blk < 256){ // Wal4 (rows 0..511: [h|ctx])
    unsigned u = blk*256u + tid; int kc = u>>10, c = (u>>2)&255, i = u&3, row = 8*kc+2*i;
    ws[OFF_WAL4/4 + u] = pk2(Walm[row*256+c], Walm[(row+1)*256+c]); return; } blk -= 256;
  if (blk < 128){ // Wm4
    unsigned u = blk*256u + tid; int kc = u>>10, c = (u>>2)&255, i = u&3, row = 8*kc+2*i;
    ws[OFF_WM4/4 + u] = pk2(Wmm[row*256+c], Wmm[(row+1)*256+c]); return; } blk -= 128;
  if (blk < 384){ unsigned u = blk*256u + tid; int k2 = u/768, c = u%768;
    ws[OFF_WX1P/4 + u] = pk2(Wx1[2*k2*768+c], Wx1[(2*k2+1)*768+c]); return; } blk -= 384;
  if (blk < 384){ unsigned u = blk*256u + tid; int k2 = u/768, c = u%768;
    ws[OFF_WH1P/4 + u] = pk2(Wh1[2*k2*768+c], Wh1[(2*k2+1)*768+c]); return; } blk -= 384;
  if (blk < 384){ unsigned u = blk*256u + tid; int k2 = u/768, c = u%768;
    ws[OFF_WX2P/4 + u] = pk2(Wx2[2*k2*768+c], Wx2[(2*k2+1)*768+c]); return; } blk -= 384;
  if (blk < 384){ unsigned u = blk*256u + tid; int k2 = u/768, c = u%768;
    ws[OFF_WH2P/4 + u] = pk2(Wh2[2*k2*768+c], Wh2[(2*k2+1)*768+c]); return; } blk -= 384;
  if (blk < 200){ unsigned u = blk*256u + tid; int k2 = u/400, c = u%400;
    ws[OFF_WOUTP/4 + u] = pk2(Woutm[2*k2*400+c], Woutm[(2*k2+1)*400+c]); return; } blk -= 200;
  { // mem_e2: pairs along e: [b][kc][d][i] = half2(mem[b][8kc+2i][d], mem[b][8kc+2i+1][d])
    unsigned u = blk*256u + tid; int b = u>>15, kc = (u>>10)&31, d = (u>>2)&255, i = u&3;
    int e0 = 8*kc+2*i;
    ws[OFF_MEME2/4 + u] = pk2(memory[((size_t)(b*256+e0))*256 + d],
                              memory[((size_t)(b*256+e0+1))*256 + d]);
  }
}

// ---------- keys kernel: keys_s[b][e][a] = (mem[b]@Wm)[e][a]*2log2e, swizzled ----------
__global__ __launch_bounds__(256) void keys_kernel(const float* memory, const unsigned* wm4, __half* keysH)
{
  int tid = threadIdx.x;
  int b = blockIdx.x >> 3, et = blockIdx.x & 7, e0 = et*32, a = tid;
  __shared__ __align__(16) unsigned a2[32][4];
  float acc[32];
  #pragma unroll
  for (int e=0;e<32;e++) acc[e]=0.f;
  for (int kc=0;kc<32;kc++){
    if (tid < 128){
      int e = tid>>2, i = tid&3;
      const float* mr = memory + (size_t)(b*256 + e0+e)*256 + 8*kc + 2*i;
      a2[e][i] = pk2(mr[0], mr[1]);
    }
    __syncthreads();
    uint4 wv = ((const uint4*)wm4)[kc*256 + a];
    #pragma unroll
    for (int e=0;e<32;e++){ uint4 uv = *((const uint4*)a2[e]); DOT4(acc[e], uv, wv); }
    __syncthreads();
  }
  // swizzled store so decoder reads coalesce: uint-slot (i4*4+s)*4+k holds pair P=s*32+i4*4+k
  __half* base = keysH + (size_t)(b*256 + e0)*256;
  int P = a>>1, lo = a&1, k = P&3, i4 = (P>>2)&7, sw = P>>5;
  int hidx = ((i4*4+sw)*4 + k)*2 + lo;
  #pragma unroll
  for (int e=0;e<32;e++) base[(size_t)e*256 + hidx] = __float2half(acc[e]*2.88539008f);
}

// ---------- xg kernel: xg[b][t][c] = x_t @ WxX + b_dec ----------
__global__ __launch_bounds__(768) void xg_kernel(const float* inputs, const float* bdec,
                                                 const unsigned* wxx4, __half* xg)
{
  int tid = threadIdx.x;
  int b = blockIdx.x >> 3, t0 = (blockIdx.x & 7)*25;
  __shared__ __align__(16) unsigned xp[25][200];
  for (int idx = tid; idx < 5000; idx += 768){
    int tt = idx/200, kk = idx%200;
    float2 v = ((const float2*)(inputs + (size_t)(b*200 + t0+tt)*400))[kk];
    xp[tt][kk] = pk2(v.x, v.y);
  }
  __syncthreads();
  int c = tid;
  float bd = bdec[c];
  float acc[25];
  #pragma unroll
  for (int tt=0;tt<25;tt++) acc[tt]=bd;
  for (int kc=0;kc<50;kc++){
    uint4 wv = ((const uint4*)wxx4)[kc*768 + c];
    #pragma unroll
    for (int tt=0;tt<25;tt++){ uint4 xv = ((const uint4*)xp[tt])[kc]; DOT4(acc[tt], xv, wv); }
  }
  __half* xr = xg + (size_t)b*153600;
  #pragma unroll
  for (int tt=0;tt<25;tt++) xr[(size_t)(t0+tt)*768 + c] = __float2half(acc[tt]);
}

// ---------- decoder: 32 wgs (1/b) x 1024 thr, 200 steps ----------
__global__ __launch_bounds__(1024) void decoder_kernel(
    const float* va, const unsigned* wxa4, const unsigned* wh4, const unsigned* wq4,
    const unsigned* wal4, const unsigned* me2, const __half* keysAll, const __half* xgAll,
    float* attn_ws, float* out)
{
  const int tid = threadIdx.x, b = blockIdx.x;
  __shared__ __align__(16) float h_f[256], ga[768], ghl[768], qf[256], scf[256], alf[256], cf[256], vf[256];
  __shared__ __align__(16) unsigned actA2[128], actH2[128], al2[128], ctx2[128];
  __shared__ float red[8];
  __shared__ float Vsum_s;

  const __half* keysH = keysAll + (size_t)b*65536;
  const __half* xgb   = xgAll   + (size_t)b*153600;
  float* attnb = attn_ws + (size_t)b*51200;

  if (tid<256){ vf[tid]=va[tid]; scf[tid]=va[tid]; h_f[tid]=0.f; }
  if (tid<128){ actA2[tid]=0u; actH2[tid]=0u; }
  __syncthreads();
  for (int sR=128; sR>0; sR>>=1){ if (tid<sR) scf[tid]+=scf[tid+sR]; __syncthreads(); }
  if (tid==0) Vsum_s = scf[0];
  __syncthreads();

  for (int t=0; t<TDEC; t++){
    // P1: gate pre-activations: ga = xg + attn@WxA ; ghl = h@Wh
    if (tid < 768){
      int c = tid;
      float aa = __half2float(xgb[(size_t)t*768 + c]);
      float ah = 0.f;
      for (int kc=0;kc<32;kc++){
        uint4 wv = ((const uint4*)wxa4)[kc*768+c];  uint4 uv = ((const uint4*)actA2)[kc]; DOT4(aa,uv,wv);
        uint4 wv2= ((const uint4*)wh4)[kc*768+c];   uint4 vv = ((const uint4*)actH2)[kc]; DOT4(ah,vv,wv2);
      }
      ga[c]=aa; ghl[c]=ah;
    }
    __syncthreads();
    // P2: gates + h update
    if (tid<256){
      int j=tid;
      float z = sigf(ga[j]+ghl[j]);
      float r = sigf(ga[j+256]+ghl[j+256]);
      float n = tanhf_(ga[j+512] + r*ghl[j+512]);
      h_f[j] = z*h_f[j] + (1.f-z)*n;
    }
    __syncthreads();
    if (tid<128) actH2[tid] = pk2(h_f[2*tid], h_f[2*tid+1]);
    __syncthreads();
    // P3: q = h@Wq (scaled by 2log2e to match pre-scaled keys)
    if (tid<256){
      int a=tid; float acc=0.f;
      for (int kc=0;kc<32;kc++){
        uint4 wv = ((const uint4*)wq4)[kc*256+a]; uint4 uv = ((const uint4*)actH2)[kc]; DOT4(acc,uv,wv);
      }
      qf[a] = acc*2.88539008f;
    }
    __syncthreads();
    // P4: scores[e] = Vsum - 2*sum_a v[a]/(1+exp2(keys_s+q_s))
    {
      int e = tid>>2, sq = tid&3;
      const uint4* kb = (const uint4*)(keysH + (size_t)e*256);
      float acc = 0.f;
      #pragma unroll
      for (int i4=0;i4<8;i4++){
        uint4 kk = kb[i4*4+sq];
        int P0 = sq*32 + i4*4;
        #pragma unroll
        for (int k=0;k<4;k++){
          unsigned ku = (k==0)?kk.x:(k==1)?kk.y:(k==2)?kk.z:kk.w;
          float2 qv = ((const float2*)qf)[P0+k];
          float2 vv = ((const float2*)vf)[P0+k];
          __half2 hh = __builtin_bit_cast(__half2, ku);
          float w0 = FEXP2(__low2float(hh)  + qv.x); acc = fmaf(vv.x, FRCP(1.f+w0), acc);
          float w1 = FEXP2(__high2float(hh) + qv.y); acc = fmaf(vv.y, FRCP(1.f+w1), acc);
        }
      }
      acc += __shfl_xor(acc,1); acc += __shfl_xor(acc,2);
      if (sq==0) scf[e] = Vsum_s - 2.f*acc;
    }
    __syncthreads();
    // P5: softmax + alignments output (transposed)
    {
      float x = (tid<256)? scf[tid] : -1e30f;
      if (tid<256){
        float mx = x;
        for (int off=32; off; off>>=1) mx = fmaxf(mx, __shfl_xor(mx, off));
        if ((tid&63)==0) red[tid>>6] = mx;
      }
      __syncthreads();
      if (tid<256){
        float gm = fmaxf(fmaxf(red[0],red[1]), fmaxf(red[2],red[3]));
        float p = FEXP2((x-gm)*1.44269504f);
        alf[tid] = p;
        float sSum = p;
        for (int off=32; off; off>>=1) sSum += __shfl_xor(sSum, off);
        if ((tid&63)==0) red[4+(tid>>6)] = sSum;
      }
      __syncthreads();
      if (tid<256){
        float S = red[4]+red[5]+red[6]+red[7];
        float al = alf[tid]*FRCP(S);
        alf[tid] = al;
        out[AOFF + (size_t)b*51200 + (size_t)tid*200 + t] = al;
      }
    }
    __syncthreads();
    if (tid<128) al2[tid] = pk2(alf[2*tid], alf[2*tid+1]);
    __syncthreads();
    // P6: ctx[d] = sum_e align[e]*mem[e][d]
    if (tid<256){
      int d=tid; float acc=0.f;
      for (int kc=0;kc<32;kc++){
        uint4 wv = ((const uint4*)me2)[(size_t)(b*32+kc)*256+d];
        uint4 uv = ((const uint4*)al2)[kc];
        DOT4(acc,uv,wv);
      }
      cf[d]=acc;
    }
    __syncthreads();
    if (tid<128) ctx2[tid] = pk2(cf[2*tid], cf[2*tid+1]);
    __syncthreads();
    // P7: attn = [h|ctx]@Wal
    if (tid<256){
      int c=tid; float acc=0.f;
      for (int kc=0;kc<64;kc++){
        uint4 wv = ((const uint4*)wal4)[kc*256+c];
        uint4 uv = (kc<32)? ((const uint4*)actH2)[kc] : ((const uint4*)ctx2)[kc-32];
        DOT4(acc,uv,wv);
      }
      attnb[(size_t)t*256 + c] = acc;
      ga[c] = acc; // reuse for pack
    }
    __syncthreads();
    if (tid<128) actA2[tid] = pk2(ga[2*tid], ga[2*tid+1]);
    __syncthreads();
  }
}

// ---------- GRU kernel: 32 groups x 8 members; VGPR-resident slices; 1 sync/step ----------
// member m owns hidden j in [m*32, m*32+32) (gate cols g*256+m*32+jj).
// GRU2 (Woutp!=nullptr): input = attn+y1, also folds mel = (out1+y2)@W_out + b_out.
__global__ __launch_bounds__(256) void gru_kernel(
    const float* xin_a, const float* xin_b,
    const unsigned* Wxp, const unsigned* Whp, const float* bias,
    float* yex, unsigned* cnt,
    const unsigned* Woutp, const float* bout, float* melout)
{
  const int tid = threadIdx.x;
  const int b = blockIdx.x & 31, m = blockIdx.x >> 5;
  const int c = (tid<192)? tid%96 : 0, s = (tid<192)? tid/96 : 0;
  const int col = (c>>5)*256 + m*32 + (c&31);

  unsigned wx[64], wh[64];
  if (tid<192){
    #pragma unroll
    for (int i=0;i<64;i++){ wx[i] = Wxp[(size_t)(s*64+i)*768 + col]; wh[i] = Whp[(size_t)(s*64+i)*768 + col]; }
  }
  unsigned wo[32];
  if (Woutp && tid<200){
    int mc = m*50 + tid%50, so = tid/50;
    #pragma unroll
    for (int i=0;i<32;i++) wo[i] = Woutp[(size_t)(so*32+i)*400 + mc];
  }
  __shared__ float bsl[96], bml[50];
  __shared__ __align__(16) float h_f[256], o1f[256];
  __shared__ __align__(16) unsigned h2[128], in2[128];
  __shared__ float pax[192], pah[192], pm[200];
  if (tid<96) bsl[tid] = bias[(tid>>5)*256 + m*32 + (tid&31)];
  if (Woutp && tid<50) bml[tid] = bout[m*50+tid];
  if (tid<256) h_f[tid]=0.f;
  if (tid<128) h2[tid]=0u;
  __syncthreads();

  const float* xa = xin_a + (size_t)b*51200;
  const float* xb = xin_b ? xin_b + (size_t)b*51200 : nullptr;
  float* ye = yex + (size_t)b*51200;
  unsigned* cg = cnt + b;

  for (int t=0;t<TDEC;t++){
    if (tid<128){
      float2 av = ((const float2*)(xa + (size_t)t*256))[tid];
      float x0 = av.x, x1 = av.y;
      if (xb){ float2 bv = ((const float2*)(xb + (size_t)t*256))[tid]; x0 += bv.x; x1 += bv.y;
               o1f[2*tid] = x0; o1f[2*tid+1] = x1; }
      in2[tid] = pk2(x0,x1);
    }
    __syncthreads();
    if (tid<192){
      float ax=0.f, ah=0.f;
      #pragma unroll
      for (int i4=0;i4<16;i4++){
        uint4 uv = ((const uint4*)in2)[s*16+i4];
        ax = fdot2u(uv.x, wx[i4*4+0], ax); ax = fdot2u(uv.y, wx[i4*4+1], ax);
        ax = fdot2u(uv.z, wx[i4*4+2], ax); ax = fdot2u(uv.w, wx[i4*4+3], ax);
        uint4 vv = ((const uint4*)h2)[s*16+i4];
        ah = fdot2u(vv.x, wh[i4*4+0], ah); ah = fdot2u(vv.y, wh[i4*4+1], ah);
        ah = fdot2u(vv.z, wh[i4*4+2], ah); ah = fdot2u(vv.w, wh[i4*4+3], ah);
      }
      pax[tid]=ax; pah[tid]=ah;
    }
    __syncthreads();
    if (tid<32){
      int j=tid;
      float gaz = pax[j]    + pax[96+j]  + bsl[j];
      float ghz = pah[j]    + pah[96+j];
      float gar = pax[32+j] + pax[128+j] + bsl[32+j];
      float ghr = pah[32+j] + pah[128+j];
      float gan = pax[64+j] + pax[160+j] + bsl[64+j];
      float ghn = pah[64+j] + pah[160+j];
      float z = sigf(gaz+ghz), r = sigf(gar+ghr);
      float n = tanhf_(gan + r*ghn);
      float hn = z*h_f[m*32+j] + (1.f-z)*n;
      __hip_atomic_store(ye + (size_t)t*256 + m*32 + j, hn, __ATOMIC_RELAXED, __HIP_MEMORY_SCOPE_AGENT);
    }
    __syncthreads();
    if (tid==0){
      __threadfence();
      __hip_atomic_fetch_add(cg, 1u, __ATOMIC_RELEASE, __HIP_MEMORY_SCOPE_AGENT);
      unsigned tgt = 8u*(t+1);
      while (__hip_atomic_load(cg, __ATOMIC_ACQUIRE, __HIP_MEMORY_SCOPE_AGENT) < tgt)
        __builtin_amdgcn_s_sleep(1);
    }
    __syncthreads();
    if (tid<256) h_f[tid] = __hip_atomic_load(ye + (size_t)t*256 + tid, __ATOMIC_RELAXED, __HIP_MEMORY_SCOPE_AGENT);
    __syncthreads();
    if (tid<128) h2[tid] = pk2(h_f[2*tid], h_f[2*tid+1]);
    if (Woutp){
      __syncthreads();
      if (tid<128) in2[tid] = pk2(o1f[2*tid]+h_f[2*tid], o1f[2*tid+1]+h_f[2*tid+1]); // out2 pairs
      __syncthreads();
      if (tid<200){
        int so = tid/50;
        float acc=0.f;
        #pragma unroll
        for (int i4=0;i4<8;i4++){
          uint4 uv = ((const uint4*)in2)[so*8+i4];
          acc = fdot2u(uv.x, wo[i4*4+0], acc); acc = fdot2u(uv.y, wo[i4*4+1], acc);
          acc = fdot2u(uv.z, wo[i4*4+2], acc); acc = fdot2u(uv.w, wo[i4*4+3], acc);
        }
        pm[tid]=acc;
      }
      __syncthreads();
      if (tid<50){
        float mel = pm[tid]+pm[50+tid]+pm[100+tid]+pm[150+tid]+bml[tid];
        melout[(size_t)b*80000 + (size_t)t*400 + m*50 + tid] = mel;
      }
    }
  }
}

// ---------- launch ----------
extern "C" void kernel_launch(void* const* d_in, const int* in_sizes, int n_in,
                              void* d_out, int out_size, void* d_ws, size_t ws_size,
                              hipStream_t stream) {
  if (ws_size < WS_NEED) return; // out stays poisoned -> clear failure, no corruption
  const float* inputs = (const float*)d_in[0];
  const float* memory = (const float*)d_in[1];
  const float* Wq  = (const float*)d_in[2];
  const float* Wm  = (const float*)d_in[3];
  const float* va  = (const float*)d_in[4];
  const float* Wal = (const float*)d_in[5];
  const float* Wxd = (const float*)d_in[6];
  const float* Whd = (const float*)d_in[7];
  const float* bdec= (const float*)d_in[8];
  const float* Wx1 = (const float*)d_in[9];
  const float* Wh1 = (const float*)d_in[10];
  const float* b1  = (const float*)d_in[11];
  const float* Wx2 = (const float*)d_in[12];
  const float* Wh2 = (const float*)d_in[13];
  const float* b2  = (const float*)d_in[14];
  const float* Wout= (const float*)d_in[15];
  const float* bout= (const float*)d_in[16];
  float* out = (float*)d_out;

  char* wsb = (char*)d_ws;
  unsigned* wsu = (unsigned*)d_ws;
  const unsigned* WXX4 = (const unsigned*)(wsb + OFF_WXX4);
  const unsigned* WXA4 = (const unsigned*)(wsb + OFF_WXA4);
  const unsigned* WH4  = (const unsigned*)(wsb + OFF_WH4);
  const unsigned* WQ4  = (const unsigned*)(wsb + OFF_WQ4);
  const unsigned* WAL4 = (const unsigned*)(wsb + OFF_WAL4);
  const unsigned* WM4  = (const unsigned*)(wsb + OFF_WM4);
  const unsigned* WX1P = (const unsigned*)(wsb + OFF_WX1P);
  const unsigned* WH1P = (const unsigned*)(wsb + OFF_WH1P);
  const unsigned* WX2P = (const unsigned*)(wsb + OFF_WX2P);
  const unsigned* WH2P = (const unsigned*)(wsb + OFF_WH2P);
  const unsigned* WOUTP= (const unsigned*)(wsb + OFF_WOUTP);
  const unsigned* ME2  = (const unsigned*)(wsb + OFF_MEME2);
  __half* KEYS = (__half*)(wsb + OFF_KEYS);
  __half* XG   = (__half*)(wsb + OFF_XG);
  float* ATTN  = (float*)(wsb + OFF_ATTN);
  float* Y1    = (float*)(wsb + OFF_Y1);
  float* Y2    = (float*)(wsb + OFF_Y2);
  unsigned* CNT1 = (unsigned*)wsb;
  unsigned* CNT2 = CNT1 + 32;

  (void)hipMemsetAsync(d_ws, 0, 256, stream);
  pack_kernel<<<7712, 256, 0, stream>>>(Wxd, Whd, Wq, Wal, Wm, Wx1, Wh1, Wx2, Wh2, Wout, memory, wsu);
  keys_kernel<<<256, 256, 0, stream>>>(memory, WM4, KEYS);
  xg_kernel<<<256, 768, 0, stream>>>(inputs, bdec, WXX4, XG);
  decoder_kernel<<<NB, 1024, 0, stream>>>(va, WXA4, WH4, WQ4, WAL4, ME2, KEYS, XG, ATTN, out);
  gru_kernel<<<256, 256, 0, stream>>>(ATTN, nullptr, WX1P, WH1P, b1, Y1, CNT1, nullptr, nullptr, nullptr);
  gru_kernel<<<256, 256, 0, stream>>>(ATTN, Y1,      WX2P, WH2P, b2, Y2, CNT2, WOUTP, bout, out);
}